// Round 2
// baseline (147.334 us; speedup 1.0000x reference)
//
#include <hip/hip_runtime.h>

#define B_ROWS 2048
#define S_LEN  8192
#define PER_LANE 16
#define WPB 8                          // waves per block (512 threads)
#define CHUNK (64 * PER_LANE)          // 1024 elements per wave
#define NBLOCKS B_ROWS                 // one row per block; 8 waves cover 8192

// ---- compile-time decay constants ----
constexpr double cpowi(double b, int e) { double r = 1.0; for (int i = 0; i < e; ++i) r *= b; return r; }
constexpr float tof(double x) { return (x < 1.2e-38 && x > -1.2e-38) ? 0.0f : (float)x; }

// u-space EMA: u = ema / alpha, update u' = W*u + x  (W = 1 - alpha)
#define W0f 0.9f
#define W1f 0.7f
#define W2f 0.4f
#define IA0 10.0f              // 1/alpha
#define IA1 (1.0f / 0.3f)
#define IA2 (1.0f / 0.6f)
#define SE0 0.2f               // 2*alpha   (huber accumulates 2*h; 0.5 folded into final weights)
#define SE1 0.6f
#define SE2 1.2f
constexpr float NA0 = -(0.1f * 0.1f);   // -alpha^2
constexpr float NA1 = -(0.3f * 0.3f);
constexpr float NA2 = -(0.6f * 0.6f);

// Kogge-Stone decays D^(16*2^k), D=(1-alpha). Steps whose coefficient < ~1e-10
// cannot change an fp32 value of O(1) magnitude -> pruned at compile time.
constexpr float D0_1 = tof(cpowi(0.9, 16)),  D0_2 = tof(cpowi(0.9, 32));
constexpr float D0_4 = tof(cpowi(0.9, 64)),  D0_8 = tof(cpowi(0.9, 128));
constexpr float D1_1 = tof(cpowi(0.7, 16)),  D1_2 = tof(cpowi(0.7, 32));
constexpr float D2_1 = tof(cpowi(0.4, 16));

// log2(1-alpha) for analytic carry weights (1-a)^(16*lane) = exp2(16*lane*log2(1-a))
#define L2_0 (-0.15200309344504997f)
#define L2_1 (-0.51457317282975830f)
#define L2_2 (-1.32192809488736230f)

__device__ __forceinline__ float scan4(float v, int lane, float d1, float d2, float d4, float d8) {
    float u;
    u = __shfl_up(v, 1); v += (lane >= 1 ? d1 : 0.0f) * u;
    u = __shfl_up(v, 2); v += (lane >= 2 ? d2 : 0.0f) * u;
    u = __shfl_up(v, 4); v += (lane >= 4 ? d4 : 0.0f) * u;
    u = __shfl_up(v, 8); v += (lane >= 8 ? d8 : 0.0f) * u;
    return v;
}
__device__ __forceinline__ float scan2(float v, int lane, float d1, float d2) {
    float u;
    u = __shfl_up(v, 1); v += (lane >= 1 ? d1 : 0.0f) * u;
    u = __shfl_up(v, 2); v += (lane >= 2 ? d2 : 0.0f) * u;
    return v;
}
__device__ __forceinline__ float scan1(float v, int lane, float d1) {
    float u;
    u = __shfl_up(v, 1); v += (lane >= 1 ? d1 : 0.0f) * u;
    return v;
}

__global__ void __launch_bounds__(512) msl_main(const float* __restrict__ pred,
                                                const float* __restrict__ targ,
                                                float* __restrict__ partial) {
    const int lane = threadIdx.x & 63;
    const int wave = threadIdx.x >> 6;
    const float* __restrict__ prow = pred + (size_t)blockIdx.x * S_LEN;
    const float* __restrict__ trow = targ + (size_t)blockIdx.x * S_LEN;
    const int base = wave * CHUNK + lane * PER_LANE;

    float xp[PER_LANE], xt[PER_LANE];
    const float4* p4 = reinterpret_cast<const float4*>(prow + base);
    const float4* t4 = reinterpret_cast<const float4*>(trow + base);
#pragma unroll
    for (int j = 0; j < PER_LANE / 4; ++j) {
        float4 a = p4[j];
        float4 b = t4[j];
        xp[4 * j + 0] = a.x; xp[4 * j + 1] = a.y; xp[4 * j + 2] = a.z; xp[4 * j + 3] = a.w;
        xt[4 * j + 0] = b.x; xt[4 * j + 1] = b.y; xt[4 * j + 2] = b.z; xt[4 * j + 3] = b.w;
    }

    const bool w0   = (wave == 0);
    const bool lz   = (lane == 0);
    const bool head = w0 && lz;   // owns global element 0

    // ---- pass 1: lane-local EMA in u-space, zero carry-in.
    // head: u_init = x0/a; its j=0 update W*(x0/a)+x0 == x0/a (to fp32 noise),
    // matching pe[0] = x[0]. ----
    float Mp0 = head ? xp[0] * IA0 : 0.0f;
    float Mp1 = head ? xp[0] * IA1 : 0.0f;
    float Mp2 = head ? xp[0] * IA2 : 0.0f;
    float Mt0 = head ? xt[0] * IA0 : 0.0f;
    float Mt1 = head ? xt[0] * IA1 : 0.0f;
    float Mt2 = head ? xt[0] * IA2 : 0.0f;
#pragma unroll
    for (int j = 0; j < PER_LANE; ++j) {
        Mp0 = fmaf(W0f, Mp0, xp[j]);
        Mp1 = fmaf(W1f, Mp1, xp[j]);
        Mp2 = fmaf(W2f, Mp2, xp[j]);
        Mt0 = fmaf(W0f, Mt0, xt[j]);
        Mt1 = fmaf(W1f, Mt1, xt[j]);
        Mt2 = fmaf(W2f, Mt2, xt[j]);
    }

    // ---- wave scans (pruned per decay rate) ----
    float vp0 = scan4(Mp0, lane, D0_1, D0_2, D0_4, D0_8);
    float vp1 = scan2(Mp1, lane, D1_1, D1_2);
    float vp2 = scan1(Mp2, lane, D2_1);
    float vt0 = scan4(Mt0, lane, D0_1, D0_2, D0_4, D0_8);
    float vt1 = scan2(Mt1, lane, D1_1, D1_2);
    float vt2 = scan1(Mt2, lane, D2_1);

    // ---- publish chunk-exit states (u-space). (1-a)^1024 == 0.0f exactly,
    // so exits are carry-in independent. ----
    __shared__ float sex[WPB][6];
    if (lane == 63) {
        sex[wave][0] = vp0; sex[wave][1] = vp1; sex[wave][2] = vp2;
        sex[wave][3] = vt0; sex[wave][4] = vt1; sex[wave][5] = vt2;
    }
    __syncthreads();

    float Cp0 = 0.f, Cp1 = 0.f, Cp2 = 0.f, Ct0 = 0.f, Ct1 = 0.f, Ct2 = 0.f;
    if (wave > 0) {
        Cp0 = sex[wave - 1][0]; Cp1 = sex[wave - 1][1]; Cp2 = sex[wave - 1][2];
        Ct0 = sex[wave - 1][3]; Ct1 = sex[wave - 1][4]; Ct2 = sex[wave - 1][5];
    }

    // analytic carry fold-in: exclusive carry y_l = v_{l-1} + (1-a)^(16*l) * C
    const float e  = (float)(PER_LANE * lane);
    const float G0 = exp2f(e * L2_0);
    const float G1 = exp2f(e * L2_1);
    const float G2 = exp2f(e * L2_2);

    float up0 = __shfl_up(vp0, 1), up1 = __shfl_up(vp1, 1), up2 = __shfl_up(vp2, 1);
    float ut0 = __shfl_up(vt0, 1), ut1 = __shfl_up(vt1, 1), ut2 = __shfl_up(vt2, 1);

    float yp0 = lz ? (w0 ? xp[0] * IA0 : Cp0) : fmaf(G0, Cp0, up0);
    float yp1 = lz ? (w0 ? xp[0] * IA1 : Cp1) : fmaf(G1, Cp1, up1);
    float yp2 = lz ? (w0 ? xp[0] * IA2 : Cp2) : fmaf(G2, Cp2, up2);
    float yt0 = lz ? (w0 ? xt[0] * IA0 : Ct0) : fmaf(G0, Ct0, ut0);
    float yt1 = lz ? (w0 ? xt[0] * IA1 : Ct1) : fmaf(G1, Ct1, ut1);
    float yt2 = lz ? (w0 ? xt[0] * IA2 : Ct2) : fmaf(G2, Ct2, ut2);

    // ---- pass 2: replay in u-space with exact carry; huber on scaled deltas.
    // pd = a*du_p, td = a*du_t:  dir<0 <=> dup*dut<0 ; se = a|dup-dut| ;
    // quad = 0.5*max(1 - a^2*dup*dut, 0)^2. Accumulate 2*h, weight 0.5 later. ----
    float acc0 = 0.f, acc1 = 0.f, acc2 = 0.f;
    const float skip = head ? 0.0f : 1.0f;  // no loss term for global t=0
#pragma unroll
    for (int j = 0; j < PER_LANE; ++j) {
        float n, dup0, dut0, dup1, dut1, dup2, dut2;
        n = fmaf(W0f, yp0, xp[j]); dup0 = n - yp0; yp0 = n;
        n = fmaf(W0f, yt0, xt[j]); dut0 = n - yt0; yt0 = n;
        n = fmaf(W1f, yp1, xp[j]); dup1 = n - yp1; yp1 = n;
        n = fmaf(W1f, yt1, xt[j]); dut1 = n - yt1; yt1 = n;
        n = fmaf(W2f, yp2, xp[j]); dup2 = n - yp2; yp2 = n;
        n = fmaf(W2f, yt2, xt[j]); dut2 = n - yt2; yt2 = n;

        float m0 = dup0 * dut0, m1 = dup1 * dut1, m2 = dup2 * dut2;
        float se0 = SE0 * fabsf(dup0 - dut0);
        float se1 = SE1 * fabsf(dup1 - dut1);
        float se2 = SE2 * fabsf(dup2 - dut2);
        float mm0 = fmaxf(fmaf(NA0, m0, 1.0f), 0.0f);
        float mm1 = fmaxf(fmaf(NA1, m1, 1.0f), 0.0f);
        float mm2 = fmaxf(fmaf(NA2, m2, 1.0f), 0.0f);
        float h0 = (m0 < 0.0f) ? se0 : mm0 * mm0;
        float h1 = (m1 < 0.0f) ? se1 : mm1 * mm1;
        float h2 = (m2 < 0.0f) ? se2 : mm2 * mm2;
        if (j == 0) { h0 *= skip; h1 *= skip; h2 *= skip; }
        acc0 += h0; acc1 += h1; acc2 += h2;
    }

    // accumulated 2*h -> weights are 0.5*{0.5,0.3,0.2}
    float wacc = 0.25f * acc0 + 0.15f * acc1 + 0.10f * acc2;
#pragma unroll
    for (int o = 32; o > 0; o >>= 1) wacc += __shfl_down(wacc, o);

    __shared__ float sred[WPB];
    if (lz) sred[wave] = wacc;
    __syncthreads();
    if (threadIdx.x == 0) {
        float s = 0.f;
#pragma unroll
        for (int i = 0; i < WPB; ++i) s += sred[i];
        partial[blockIdx.x] = s;
    }
}

__global__ void __launch_bounds__(256) msl_reduce(const float* __restrict__ partial,
                                                  float* __restrict__ out) {
    const int tid = threadIdx.x;
    float v = 0.f;
#pragma unroll
    for (int k = 0; k < NBLOCKS / 256; ++k) v += partial[tid + 256 * k];
#pragma unroll
    for (int o = 32; o > 0; o >>= 1) v += __shfl_down(v, o);
    __shared__ float s[4];
    if ((tid & 63) == 0) s[tid >> 6] = v;
    __syncthreads();
    if (tid == 0)
        out[0] = (s[0] + s[1] + s[2] + s[3]) *
                 (float)(1.0 / ((double)(S_LEN - 1) * (double)B_ROWS));
}

extern "C" void kernel_launch(void* const* d_in, const int* in_sizes, int n_in,
                              void* d_out, int out_size, void* d_ws, size_t ws_size,
                              hipStream_t stream) {
    const float* pred = (const float*)d_in[0];
    const float* targ = (const float*)d_in[1];
    float* out = (float*)d_out;
    float* partial = (float*)d_ws;  // 2048 floats = 8 KB

    msl_main<<<NBLOCKS, 512, 0, stream>>>(pred, targ, partial);
    msl_reduce<<<1, 256, 0, stream>>>(partial, out);
}

// Round 3
// 144.092 us; speedup vs baseline: 1.0225x; 1.0225x over previous
//
#include <hip/hip_runtime.h>

#define B_ROWS 2048
#define S_LEN  8192
#define PER_LANE 8
#define TPB 1024
#define WPB 16                         // waves per block
#define CHUNK (64 * PER_LANE)          // 512 elements per wave
#define NBLOCKS B_ROWS                 // one row per block; 16 waves cover 8192

// ---- compile-time decay constants ----
constexpr double cpowi(double b, int e) { double r = 1.0; for (int i = 0; i < e; ++i) r *= b; return r; }
constexpr float tof(double x) { return (x < 1.2e-38 && x > -1.2e-38) ? 0.0f : (float)x; }

// u-space EMA: u = ema / alpha, update u' = W*u + x  (W = 1 - alpha)
#define W0f 0.9f
#define W1f 0.7f
#define W2f 0.4f
#define IA0 10.0f              // 1/alpha
#define IA1 (1.0f / 0.3f)
#define IA2 (1.0f / 0.6f)
#define SE0 0.2f               // 2*alpha (huber accumulates 2*h; 0.5 folded into final weights)
#define SE1 0.6f
#define SE2 1.2f
constexpr float NA0 = -(0.1f * 0.1f);   // -alpha^2
constexpr float NA1 = -(0.3f * 0.3f);
constexpr float NA2 = -(0.6f * 0.6f);

// Kogge-Stone decays D^(8*2^k), D=(1-alpha). Steps with coeff*|v|max < ~1e-9
// cannot move fp32 values of this magnitude -> pruned at compile time.
constexpr float D0_1 = tof(cpowi(0.9, 8)),  D0_2 = tof(cpowi(0.9, 16));
constexpr float D0_4 = tof(cpowi(0.9, 32)), D0_8 = tof(cpowi(0.9, 64));
constexpr float D0_16 = tof(cpowi(0.9, 128));
constexpr float D1_1 = tof(cpowi(0.7, 8)),  D1_2 = tof(cpowi(0.7, 16));
constexpr float D1_4 = tof(cpowi(0.7, 32));
constexpr float D2_1 = tof(cpowi(0.4, 8)),  D2_2 = tof(cpowi(0.4, 16));

// log2(1-alpha) for analytic carry weights (1-a)^(8*lane) = exp2(8*lane*log2(1-a))
#define L2_0 (-0.15200309344504997f)
#define L2_1 (-0.51457317282975830f)
#define L2_2 (-1.32192809488736230f)

__device__ __forceinline__ float scan5(float v, int lane, float d1, float d2, float d4,
                                       float d8, float d16) {
    float u;
    u = __shfl_up(v, 1);  v += (lane >= 1  ? d1  : 0.0f) * u;
    u = __shfl_up(v, 2);  v += (lane >= 2  ? d2  : 0.0f) * u;
    u = __shfl_up(v, 4);  v += (lane >= 4  ? d4  : 0.0f) * u;
    u = __shfl_up(v, 8);  v += (lane >= 8  ? d8  : 0.0f) * u;
    u = __shfl_up(v, 16); v += (lane >= 16 ? d16 : 0.0f) * u;
    return v;
}
__device__ __forceinline__ float scan3(float v, int lane, float d1, float d2, float d4) {
    float u;
    u = __shfl_up(v, 1); v += (lane >= 1 ? d1 : 0.0f) * u;
    u = __shfl_up(v, 2); v += (lane >= 2 ? d2 : 0.0f) * u;
    u = __shfl_up(v, 4); v += (lane >= 4 ? d4 : 0.0f) * u;
    return v;
}
__device__ __forceinline__ float scan2(float v, int lane, float d1, float d2) {
    float u;
    u = __shfl_up(v, 1); v += (lane >= 1 ? d1 : 0.0f) * u;
    u = __shfl_up(v, 2); v += (lane >= 2 ? d2 : 0.0f) * u;
    return v;
}

__global__ void __launch_bounds__(TPB) msl_main(const float* __restrict__ pred,
                                                const float* __restrict__ targ,
                                                float* __restrict__ partial) {
    const int lane = threadIdx.x & 63;
    const int wave = threadIdx.x >> 6;
    const float* __restrict__ prow = pred + (size_t)blockIdx.x * S_LEN;
    const float* __restrict__ trow = targ + (size_t)blockIdx.x * S_LEN;
    const int base = wave * CHUNK + lane * PER_LANE;

    // 16 data floats/thread: small enough to stay register-resident through both
    // passes (this is the point of PER_LANE=8 -- no remat/reload of globals).
    const float4* p4 = reinterpret_cast<const float4*>(prow + base);
    const float4* t4 = reinterpret_cast<const float4*>(trow + base);
    float4 a0 = p4[0], a1 = p4[1];
    float4 b0 = t4[0], b1 = t4[1];
    float xp[PER_LANE] = {a0.x, a0.y, a0.z, a0.w, a1.x, a1.y, a1.z, a1.w};
    float xt[PER_LANE] = {b0.x, b0.y, b0.z, b0.w, b1.x, b1.y, b1.z, b1.w};

    const bool w0   = (wave == 0);
    const bool lz   = (lane == 0);
    const bool head = w0 && lz;   // owns global element 0

    // ---- pass 1: lane-local EMA in u-space, zero carry-in.
    // head: u_init = x0/a; its j=0 update W*(x0/a)+x0 == x0/a, matching pe[0]=x[0]. ----
    float Mp0 = head ? xp[0] * IA0 : 0.0f;
    float Mp1 = head ? xp[0] * IA1 : 0.0f;
    float Mp2 = head ? xp[0] * IA2 : 0.0f;
    float Mt0 = head ? xt[0] * IA0 : 0.0f;
    float Mt1 = head ? xt[0] * IA1 : 0.0f;
    float Mt2 = head ? xt[0] * IA2 : 0.0f;
#pragma unroll
    for (int j = 0; j < PER_LANE; ++j) {
        Mp0 = fmaf(W0f, Mp0, xp[j]);
        Mp1 = fmaf(W1f, Mp1, xp[j]);
        Mp2 = fmaf(W2f, Mp2, xp[j]);
        Mt0 = fmaf(W0f, Mt0, xt[j]);
        Mt1 = fmaf(W1f, Mt1, xt[j]);
        Mt2 = fmaf(W2f, Mt2, xt[j]);
    }

    // ---- wave scans (pruned per decay rate) ----
    float vp0 = scan5(Mp0, lane, D0_1, D0_2, D0_4, D0_8, D0_16);
    float vp1 = scan3(Mp1, lane, D1_1, D1_2, D1_4);
    float vp2 = scan2(Mp2, lane, D2_1, D2_2);
    float vt0 = scan5(Mt0, lane, D0_1, D0_2, D0_4, D0_8, D0_16);
    float vt1 = scan3(Mt1, lane, D1_1, D1_2, D1_4);
    float vt2 = scan2(Mt2, lane, D2_1, D2_2);

    // ---- publish chunk-exit states (u-space). Coupling (1-a)^512 <= 3.7e-24:
    // far below half-ulp of any exit value -> zero-carry exits are bit-identical. ----
    __shared__ float sex[WPB][6];
    if (lane == 63) {
        sex[wave][0] = vp0; sex[wave][1] = vp1; sex[wave][2] = vp2;
        sex[wave][3] = vt0; sex[wave][4] = vt1; sex[wave][5] = vt2;
    }
    __syncthreads();

    float Cp0 = 0.f, Cp1 = 0.f, Cp2 = 0.f, Ct0 = 0.f, Ct1 = 0.f, Ct2 = 0.f;
    if (wave > 0) {
        Cp0 = sex[wave - 1][0]; Cp1 = sex[wave - 1][1]; Cp2 = sex[wave - 1][2];
        Ct0 = sex[wave - 1][3]; Ct1 = sex[wave - 1][4]; Ct2 = sex[wave - 1][5];
    }

    // analytic carry fold-in: exclusive carry y_l = v_{l-1} + (1-a)^(8*l) * C
    const float e  = (float)(PER_LANE * lane);
    const float G0 = exp2f(e * L2_0);
    const float G1 = exp2f(e * L2_1);
    const float G2 = exp2f(e * L2_2);

    float up0 = __shfl_up(vp0, 1), up1 = __shfl_up(vp1, 1), up2 = __shfl_up(vp2, 1);
    float ut0 = __shfl_up(vt0, 1), ut1 = __shfl_up(vt1, 1), ut2 = __shfl_up(vt2, 1);

    float yp0 = lz ? (w0 ? xp[0] * IA0 : Cp0) : fmaf(G0, Cp0, up0);
    float yp1 = lz ? (w0 ? xp[0] * IA1 : Cp1) : fmaf(G1, Cp1, up1);
    float yp2 = lz ? (w0 ? xp[0] * IA2 : Cp2) : fmaf(G2, Cp2, up2);
    float yt0 = lz ? (w0 ? xt[0] * IA0 : Ct0) : fmaf(G0, Ct0, ut0);
    float yt1 = lz ? (w0 ? xt[0] * IA1 : Ct1) : fmaf(G1, Ct1, ut1);
    float yt2 = lz ? (w0 ? xt[0] * IA2 : Ct2) : fmaf(G2, Ct2, ut2);

    // ---- pass 2: replay in u-space with exact carry; huber on scaled deltas.
    // pd = a*du_p, td = a*du_t:  dir<0 <=> dup*dut<0 ; se = a|dup-dut| ;
    // quad = 0.5*max(1 - a^2*dup*dut, 0)^2. Accumulate 2*h, weight 0.5 later. ----
    float acc0 = 0.f, acc1 = 0.f, acc2 = 0.f;
    const float skip = head ? 0.0f : 1.0f;  // no loss term for global t=0
#pragma unroll
    for (int j = 0; j < PER_LANE; ++j) {
        float n, dup0, dut0, dup1, dut1, dup2, dut2;
        n = fmaf(W0f, yp0, xp[j]); dup0 = n - yp0; yp0 = n;
        n = fmaf(W0f, yt0, xt[j]); dut0 = n - yt0; yt0 = n;
        n = fmaf(W1f, yp1, xp[j]); dup1 = n - yp1; yp1 = n;
        n = fmaf(W1f, yt1, xt[j]); dut1 = n - yt1; yt1 = n;
        n = fmaf(W2f, yp2, xp[j]); dup2 = n - yp2; yp2 = n;
        n = fmaf(W2f, yt2, xt[j]); dut2 = n - yt2; yt2 = n;

        float m0 = dup0 * dut0, m1 = dup1 * dut1, m2 = dup2 * dut2;
        float se0 = SE0 * fabsf(dup0 - dut0);
        float se1 = SE1 * fabsf(dup1 - dut1);
        float se2 = SE2 * fabsf(dup2 - dut2);
        float mm0 = fmaxf(fmaf(NA0, m0, 1.0f), 0.0f);
        float mm1 = fmaxf(fmaf(NA1, m1, 1.0f), 0.0f);
        float mm2 = fmaxf(fmaf(NA2, m2, 1.0f), 0.0f);
        float h0 = (m0 < 0.0f) ? se0 : mm0 * mm0;
        float h1 = (m1 < 0.0f) ? se1 : mm1 * mm1;
        float h2 = (m2 < 0.0f) ? se2 : mm2 * mm2;
        if (j == 0) { h0 *= skip; h1 *= skip; h2 *= skip; }
        acc0 += h0; acc1 += h1; acc2 += h2;
    }

    // accumulated 2*h -> weights are 0.5*{0.5,0.3,0.2}
    float wacc = 0.25f * acc0 + 0.15f * acc1 + 0.10f * acc2;
#pragma unroll
    for (int o = 32; o > 0; o >>= 1) wacc += __shfl_down(wacc, o);

    __shared__ float sred[WPB];
    if (lz) sred[wave] = wacc;
    __syncthreads();
    if (threadIdx.x == 0) {
        float s = 0.f;
#pragma unroll
        for (int i = 0; i < WPB; ++i) s += sred[i];
        partial[blockIdx.x] = s;
    }
}

__global__ void __launch_bounds__(256) msl_reduce(const float* __restrict__ partial,
                                                  float* __restrict__ out) {
    const int tid = threadIdx.x;
    float v = 0.f;
#pragma unroll
    for (int k = 0; k < NBLOCKS / 256; ++k) v += partial[tid + 256 * k];
#pragma unroll
    for (int o = 32; o > 0; o >>= 1) v += __shfl_down(v, o);
    __shared__ float s[4];
    if ((tid & 63) == 0) s[tid >> 6] = v;
    __syncthreads();
    if (tid == 0)
        out[0] = (s[0] + s[1] + s[2] + s[3]) *
                 (float)(1.0 / ((double)(S_LEN - 1) * (double)B_ROWS));
}

extern "C" void kernel_launch(void* const* d_in, const int* in_sizes, int n_in,
                              void* d_out, int out_size, void* d_ws, size_t ws_size,
                              hipStream_t stream) {
    const float* pred = (const float*)d_in[0];
    const float* targ = (const float*)d_in[1];
    float* out = (float*)d_out;
    float* partial = (float*)d_ws;  // 2048 floats = 8 KB

    msl_main<<<NBLOCKS, TPB, 0, stream>>>(pred, targ, partial);
    msl_reduce<<<1, 256, 0, stream>>>(partial, out);
}